// Round 6
// baseline (133.343 us; speedup 1.0000x reference)
//
#include <hip/hip_runtime.h>
#include <hip/hip_bf16.h>
#include <stdint.h>

typedef __bf16 bf16;
typedef __bf16 bf16x4 __attribute__((ext_vector_type(4)));
typedef __bf16 bf16x8 __attribute__((ext_vector_type(8)));
typedef float  f32x4  __attribute__((ext_vector_type(4)));

#define GLDS16(g, l) __builtin_amdgcn_global_load_lds(                      \
    (const __attribute__((address_space(1))) void*)(g),                     \
    (__attribute__((address_space(3))) void*)(l), 16, 0, 0)

#define BARX() do { __builtin_amdgcn_s_barrier();                            \
                    __builtin_amdgcn_sched_barrier(0); } while (0)
#define VMW(n) do { asm volatile("s_waitcnt vmcnt(" #n ")" ::: "memory");    \
                    __builtin_amdgcn_sched_barrier(0); } while (0)

// ---------------- LayerNorm: (16,1024,256) f32 -> bf16 ----------------
__global__ __launch_bounds__(256) void k_ln(const float* __restrict__ hs,
                                            const float* __restrict__ gamma,
                                            const float* __restrict__ beta,
                                            bf16* __restrict__ xb) {
  int wid = threadIdx.x >> 6, lane = threadIdx.x & 63;
  size_t row = (size_t)blockIdx.x * 4 + wid;          // 16384 rows
  const float4* p = (const float4*)(hs + row * 256);
  float4 v = p[lane];
  float s  = v.x + v.y + v.z + v.w;
  float s2 = v.x*v.x + v.y*v.y + v.z*v.z + v.w*v.w;
#pragma unroll
  for (int o = 32; o; o >>= 1) { s += __shfl_xor(s, o); s2 += __shfl_xor(s2, o); }
  float mu  = s * (1.0f/256.0f);
  float var = s2 * (1.0f/256.0f) - mu*mu;
  float rs  = rsqrtf(var + 1e-5f);
  float4 g = ((const float4*)gamma)[lane];
  float4 b = ((const float4*)beta)[lane];
  bf16x4 o4;
  o4[0] = (bf16)((v.x - mu) * rs * g.x + b.x);
  o4[1] = (bf16)((v.y - mu) * rs * g.y + b.y);
  o4[2] = (bf16)((v.z - mu) * rs * g.z + b.z);
  o4[3] = (bf16)((v.w - mu) * rs * g.w + b.w);
  *(bf16x4*)(xb + row * 256 + lane * 4) = o4;
}

// ------- transpose xb[b][kl][d] -> xt3[b][kt=kl/32][d][kl%32] (K-tile-major) -------
// GEMM-A loads B-fragments directly from global with full coalescing:
// a wave's fragment (16 d-rows x 32 k x 2B) is 1KB contiguous in this layout.
__global__ __launch_bounds__(256) void k_xt(const bf16* __restrict__ xb,
                                            bf16* __restrict__ xt3) {
  __shared__ bf16 tile[64][65];
  int kl0 = blockIdx.x * 64, d0 = blockIdx.y * 64, b = blockIdx.z;
  int t = threadIdx.x;
  int r = t >> 2, c0 = (t & 3) * 16;
  const bf16* src = xb + ((size_t)(b * 1024 + kl0 + r)) * 256 + d0 + c0;
  bf16x8 v0 = *(const bf16x8*)src;
  bf16x8 v1 = *(const bf16x8*)(src + 8);
#pragma unroll
  for (int i = 0; i < 8; i++) { tile[r][c0 + i] = v0[i]; tile[r][c0 + 8 + i] = v1[i]; }
  __syncthreads();
  int dr = t >> 2, k0 = (t & 3) * 16;
  bf16x8 w0, w1;
#pragma unroll
  for (int i = 0; i < 8; i++) { w0[i] = tile[k0 + i][dr]; w1[i] = tile[k0 + 8 + i][dr]; }
  int kk = kl0 + k0;
  bf16* dst = xt3 + ((size_t)(b * 32 + (kk >> 5)) * 256 + d0 + dr) * 32 + (kk & 31);
  *(bf16x8*)dst = w0;          // kk&31 in {0,16}: both 8-elem halves stay in-chunk
  *(bf16x8*)(dst + 8) = w1;
}

// ------- vw f32 [256][2304] -> bf16, + fused LPT class sort (block 288) -------
__global__ __launch_bounds__(256) void k_vwb(const float* __restrict__ vw,
                                             bf16* __restrict__ vwb,
                                             const float* __restrict__ centers,
                                             const float* __restrict__ spreads,
                                             int* __restrict__ sorted) {
  __shared__ int nt[72];
  int t = threadIdx.x;
  if (blockIdx.x == 288) {         // LPT: rank 72 (h,mb) classes by NT desc
    if (t < 72) {
      int h = t >> 3, mb = t & 7;
      float S00 = spreads[h*4+0], S01 = spreads[h*4+1];
      float S10 = spreads[h*4+2], S11 = spreads[h*4+3];
      float a_ = S00*S00 + S01*S01;
      float b_ = S00*S10 + S01*S11;
      float c_ = S10*S10 + S11*S11;
      float mu1 = centers[h*2+0], mu2 = centers[h*2+1];
      float det = fmaxf(a_*c_ - b_*b_, 1e-6f);
      float A_ = a_*mu1 + b_*mu2;
      float B_ = c_ + mu2 + b_*mu1;
      float ustar = (c_*A_ - b_*B_) / det;
      float lam = fmaxf(a_ - b_*b_/c_, 1e-3f);
      float M_ = __fsqrt_rn(28.0f / lam) + 1.5f;
      float lo_f = (float)(mb*4) + ustar, hi_f = lo_f + 3.0f;
      int k_lo = (int)floorf(fminf(lo_f, 31.0f) - M_);
      int k_hi = (int)ceilf(fmaxf(hi_f, 0.0f) + M_) + 1;
      if (k_lo < 0) k_lo = 0;
      if (k_hi > 32) k_hi = 32;
      if (k_hi <= k_lo) { k_lo = 0; k_hi = 32; }
      nt[t] = k_hi - k_lo;
    }
    __syncthreads();
    if (t < 72) {
      int my = nt[t], r = 0;
#pragma unroll 1
      for (int j = 0; j < 72; j++) {
        int v = nt[j];
        if (v > my || (v == my && j < t)) r++;
      }
      sorted[r] = t;          // class id = h*8 + mb
    }
    return;
  }
  int i = (blockIdx.x * 256 + t) * 8;
  float4 q0 = *(const float4*)(vw + i);
  float4 q1 = *(const float4*)(vw + i + 4);
  bf16x8 o;
  o[0]=(bf16)q0.x; o[1]=(bf16)q0.y; o[2]=(bf16)q0.z; o[3]=(bf16)q0.w;
  o[4]=(bf16)q1.x; o[5]=(bf16)q1.y; o[6]=(bf16)q1.z; o[7]=(bf16)q1.w;
  *(bf16x8*)(vwb + i) = o;
}

// -------- scores + softmax -> probs f32 (d_out) + pb2 bf16 [h][kt][ij][32] --------
__global__ __launch_bounds__(256) void k_probs(const float* __restrict__ centers,
                                               const float* __restrict__ spreads,
                                               float* __restrict__ pf,
                                               bf16* __restrict__ pb2) {
  int bid = blockIdx.x;          // ij*9 + h, 9216 blocks
  int h  = bid % 9;
  int ij = bid / 9;
  int i = ij >> 5, j = ij & 31;
  float S00 = spreads[h*4+0], S01 = spreads[h*4+1];
  float S10 = spreads[h*4+2], S11 = spreads[h*4+3];
  float a  = S00*S00 + S01*S01;
  float bq = S00*S10 + S01*S11;
  float c  = S10*S10 + S11*S11;
  float mu1 = centers[h*2+0], mu2 = centers[h*2+1];
  float u0 = a*mu1 + bq*mu2;
  float u1 = c + mu2 + bq*mu1;
  float u2 = -0.5f*a, u3 = -0.5f*c, u4 = -bq;
  int t = threadIdx.x;
  float sc[4]; float mx = -1e30f;
#pragma unroll
  for (int s = 0; s < 4; s++) {
    int kl = t*4 + s;
    float d0 = (float)((kl >> 5) - i);
    float d1 = (float)((kl & 31) - j);
    float v = d0*(u0 + u2*d0) + d1*(u1 + u3*d1) + u4*d0*d1;
    sc[s] = v; mx = fmaxf(mx, v);
  }
  __shared__ float red[8];
#pragma unroll
  for (int o = 32; o; o >>= 1) mx = fmaxf(mx, __shfl_xor(mx, o));
  int lane = t & 63, wid = t >> 6;
  if (lane == 0) red[wid] = mx;
  __syncthreads();
  mx = fmaxf(fmaxf(red[0], red[1]), fmaxf(red[2], red[3]));
  float sum = 0.f;
#pragma unroll
  for (int s = 0; s < 4; s++) { sc[s] = __expf(sc[s] - mx); sum += sc[s]; }
#pragma unroll
  for (int o = 32; o; o >>= 1) sum += __shfl_xor(sum, o);
  if (lane == 0) red[4 + wid] = sum;
  __syncthreads();
  sum = red[4] + red[5] + red[6] + red[7];
  float inv = 1.0f / sum;
  float4 o;
  o.x = sc[0]*inv; o.y = sc[1]*inv; o.z = sc[2]*inv; o.w = sc[3]*inv;
  *(float4*)(pf + (size_t)bid*1024 + t*4) = o;
  bf16x4 ob;
  ob[0] = (bf16)o.x; ob[1] = (bf16)o.y; ob[2] = (bf16)o.z; ob[3] = (bf16)o.w;
  // pb2[h][kt][ij][k%32]; thread t covers kl = t*4..t*4+3 (single 32-chunk)
  *(bf16x4*)(pb2 + ((size_t)(h*32 + (t >> 3))*1024 + ij)*32 + (t & 7)*4) = ob;
}

// ===== GEMM-A: ctx = P_h @ xt^T, 128(ij) x 256(d) tile, BK=32, K-trunc s=28 =====
// BARRIER-FREE, LDS-FREE, SINGLE-BUFFERED. R3/R5 falsified "lighten a pipe":
// the per-tile VMW+BARX drain serialized LDS+L2+MFMA (measured per-CU step ==
// their sum, invariant across traffic cuts). This version has no sync points:
// both operands load directly from K-tile-major layouts (1KB/wave coalesced
// dwordx4 per fragment), consumed fn-outer so the compiler emits progressive
// vmcnt waits. Single-buffer keeps regs ~188 (R4's dual ping-pong spilled).
// 8 independent waves/CU provide the overlap the barrier structure forbade.
__global__ __launch_bounds__(256, 2) void k_ctx(const bf16* __restrict__ pb2,
                                                const bf16* __restrict__ xt3,
                                                const float* __restrict__ centers,
                                                const float* __restrict__ spreads,
                                                const int* __restrict__ sorted,
                                                bf16* __restrict__ ctx,
                                                int b0, int nbt) {
  int r_  = blockIdx.x / nbt;                       // class rank 0..71
  int nb  = blockIdx.x % nbt;                       // batch within chunk
  int cls = sorted[r_];
  int h   = cls >> 3;
  int mb  = cls & 7;
  int ij0 = mb * 128;                               // i in [mb*4, mb*4+4)

  int t = threadIdx.x, lane = t & 63, w = t >> 6;
  int wr = w >> 1, wc = w & 1;                      // wave: rows wr*64, cols wc*128
  int g = lane >> 4, rl = lane & 15;

  // ---- Gaussian k-support bounds (uniform per block; s=28, i-span 4) ----
  float S00 = spreads[h*4+0], S01 = spreads[h*4+1];
  float S10 = spreads[h*4+2], S11 = spreads[h*4+3];
  float a_ = S00*S00 + S01*S01;
  float b_ = S00*S10 + S01*S11;
  float c_ = S10*S10 + S11*S11;
  float mu1 = centers[h*2+0], mu2 = centers[h*2+1];
  float det = fmaxf(a_*c_ - b_*b_, 1e-6f);
  float A_ = a_*mu1 + b_*mu2;
  float B_ = c_ + mu2 + b_*mu1;
  float ustar = (c_*A_ - b_*B_) / det;
  float lam = fmaxf(a_ - b_*b_/c_, 1e-3f);
  float M_ = __fsqrt_rn(28.0f / lam) + 1.5f;
  float lo_f = (float)(mb*4) + ustar, hi_f = lo_f + 3.0f;
  int k_lo = (int)floorf(fminf(lo_f, 31.0f) - M_);
  int k_hi = (int)ceilf(fmaxf(hi_f, 0.0f) + M_) + 1;
  if (k_lo < 0) k_lo = 0;
  if (k_hi > 32) k_hi = 32;
  if (k_hi <= k_lo) { k_lo = 0; k_hi = 32; }        // paranoia fallback
  const int NT = k_hi - k_lo;                       // 1..32 K-tiles of 32 kl

  f32x4 acc[4][8];
#pragma unroll
  for (int x_ = 0; x_ < 4; x_++)
#pragma unroll
    for (int y_ = 0; y_ < 8; y_++) acc[x_][y_] = (f32x4){0.f,0.f,0.f,0.f};

  // fragment bases (elements); per-kt strides: A 32768, B 8192
  const bf16* aP = pb2 + ((size_t)(h*32 + k_lo)*1024 + ij0 + wr*64 + rl)*32 + g*8;
  const bf16* bP = xt3 + ((size_t)((b0 + nb)*32 + k_lo)*256 + wc*128 + rl)*32 + g*8;

#pragma unroll 1
  for (int kt = 0; kt < NT; ++kt) {
    const bf16* ap = aP + (size_t)kt*32768;
    const bf16* bp = bP + (size_t)kt*8192;
    bf16x8 af[4], bf_[8];
#pragma unroll
    for (int fr = 0; fr < 4; fr++) af[fr]  = *(const bf16x8*)(ap + fr*512);
#pragma unroll
    for (int fn = 0; fn < 8; fn++) bf_[fn] = *(const bf16x8*)(bp + fn*512);
    // fn-outer: consumes bf_ in load order -> compiler emits progressive
    // vmcnt(N) waits; later columns' latency hides under earlier MFMAs.
#pragma unroll
    for (int fn = 0; fn < 8; fn++)
#pragma unroll
      for (int fr = 0; fr < 4; fr++)
        acc[fr][fn] = __builtin_amdgcn_mfma_f32_16x16x32_bf16(af[fr], bf_[fn], acc[fr][fn], 0, 0, 0);
  }

#pragma unroll
  for (int fr = 0; fr < 4; fr++) {
    int row = ij0 + wr*64 + fr*16 + g*4;            // ij
#pragma unroll
    for (int fn = 0; fn < 8; fn++) {
      int d = wc*128 + fn*16 + rl;                  // 0..255 within batch nb
      size_t base = ((size_t)nb*1024 + row) * 2304 + h*256 + d;
      f32x4 a4 = acc[fr][fn];
#pragma unroll
      for (int r = 0; r < 4; r++)
        ctx[base + (size_t)r*2304] = (bf16)a4[r];
    }
  }
}

// ======== GEMM-B: out[(b,ij)][m] = ctx(K2304) @ vwb^T + bias + x ========
// (R11 version — best measured.) 64 rows x FULL N=256 per block,
// 512 thr / 8 waves (wave 32x64), BK=64, 3-buf LDS (120 KB), counted VMW(5).
__global__ __launch_bounds__(512, 1) void k_out(const bf16* __restrict__ ctx,
                                                const bf16* __restrict__ vwb,
                                                const bf16* __restrict__ xb,
                                                const float* __restrict__ vbias,
                                                float* __restrict__ out, int b0) {
  __shared__ bf16 lds[3 * 20480];   // buf: A 64x64 (8KB) + B 256x64 (32KB) = 40KB
  int t = threadIdx.x, lane = t & 63, w = t >> 6;
  int wr = w >> 2, wc = w & 3;                       // wave tile: rows wr*32, cols wc*64
  int g = lane >> 4, rl = lane & 15;
  int r0 = blockIdx.x * 64;                          // chunk-local ctx row
  char* ldsb = (char*)lds;

  f32x4 acc[2][4];
#pragma unroll
  for (int x_ = 0; x_ < 2; x_++)
#pragma unroll
    for (int y_ = 0; y_ < 4; y_++) acc[x_][y_] = (f32x4){0.f,0.f,0.f,0.f};

  // staging: rr = t>>3 (64 rows), 8 chunks of 16B per 128B row, pre-swizzled
  int rr  = t >> 3;
  int csw = (t & 7) ^ (rr & 7);
  const bf16* aS = ctx + (size_t)(r0 + rr) * 2304 + csw * 8;
  const bf16* bS = vwb + (size_t)rr * 2304 + csw * 8;   // +q*64 rows per instr

#define STGO(sb, kt) do {                                                     \
    GLDS16(aS + (kt)*64, ldsb + (sb)*40960 + t*16);                           \
    _Pragma("unroll")                                                         \
    for (int q = 0; q < 4; q++)                                               \
      GLDS16(bS + (size_t)q*64*2304 + (kt)*64,                                \
             ldsb + (sb)*40960 + 8192 + q*8192 + t*16);                       \
  } while (0)

  STGO(0, 0); STGO(1, 1);
  VMW(5);                       // tile0 landed; tile1 in flight
  BARX();

  int cur = 0;
  for (int kt = 0; kt < 36; ++kt) {
    int sb = cur + 2; if (sb >= 3) sb -= 3;
    const char* ab = ldsb + cur*40960;
    const char* bb = ab + 8192;
    bf16x8 af0[2], af1[2], bf0[4], bf1[4];
#pragma unroll
    for (int fr = 0; fr < 2; fr++) {
      int row_ = wr*32 + fr*16 + rl;
      af0[fr] = *(const bf16x8*)(ab + row_*128 + (((g  ) ^ (row_&7)) << 4));
      af1[fr] = *(const bf16x8*)(ab + row_*128 + (((g+4) ^ (row_&7)) << 4));
    }
#pragma unroll
    for (int fn = 0; fn < 4; fn++) {
      int row_ = wc*64 + fn*16 + rl;
      bf0[fn] = *(const bf16x8*)(bb + row_*128 + (((g  ) ^ (row_&7)) << 4));
      bf1[fn] = *(const bf16x8*)(bb + row_*128 + (((g+4) ^ (row_&7)) << 4));
    }
    if (kt + 2 < 36) STGO(sb, kt + 2);
    BARX();
    __builtin_amdgcn_s_setprio(1);
#pragma unroll
    for (int fr = 0; fr < 2; fr++)
#pragma unroll
      for (int fn = 0; fn < 4; fn++) {
        acc[fr][fn] = __builtin_amdgcn_mfma_f32_16x16x32_bf16(af0[fr], bf0[fn], acc[fr][fn], 0, 0, 0);
        acc[fr][fn] = __builtin_amdgcn_mfma_f32_16x16x32_bf16(af1[fr], bf1[fn], acc[fr][fn], 0, 0, 0);
      }
    __builtin_amdgcn_s_setprio(0);
    if (kt + 2 < 36)      VMW(5);   // tile kt+1 landed; kt+2 in flight
    else if (kt + 1 < 36) VMW(0);   // last prefetched tile: drain all
    BARX();
    cur = cur + 1; if (cur >= 3) cur = 0;
  }
#undef STGO

#pragma unroll
  for (int fr = 0; fr < 2; fr++) {
    int rowl = r0 + wr*32 + fr*16 + g*4;
    size_t rowg = (size_t)b0*1024 + rowl;
#pragma unroll
    for (int fn = 0; fn < 4; fn++) {
      int m = wc*64 + fn*16 + rl;
      float bv = vbias[m];
      size_t base = rowg*256 + m;
#pragma unroll
      for (int r = 0; r < 4; r++)
        out[base + (size_t)r*256] = acc[fr][fn][r] + bv + (float)xb[base + (size_t)r*256];
    }
  }
}

extern "C" void kernel_launch(void* const* d_in, const int* in_sizes, int n_in,
                              void* d_out, int out_size, void* d_ws, size_t ws_size,
                              hipStream_t stream) {
  const float* hs      = (const float*)d_in[0];
  const float* centers = (const float*)d_in[1];
  const float* spreads = (const float*)d_in[2];
  const float* vw      = (const float*)d_in[3];
  const float* vb      = (const float*)d_in[4];
  const float* gamma   = (const float*)d_in[5];
  const float* beta    = (const float*)d_in[6];
  float* out     = (float*)d_out;
  float* probs_f = out + 4194304;            // output 0 is 16*32*32*256 f32

  char* ws = (char*)d_ws;
  bf16* xb  = (bf16*)ws;                     //  8,388,608 B : LN(x) bf16 [16384][256]
  bf16* pb2 = (bf16*)(ws + 8388608);         // 18,874,368 B : probs bf16 [9][32][1024][32]
  bf16* xt3 = (bf16*)(ws + 27262976);        //  8,388,608 B : x^T bf16 [16][32][256][32]
  bf16* vwb = (bf16*)(ws + 35651584);        //  1,179,648 B : vw bf16 [256][2304]
  bf16* ctx = (bf16*)(ws + 36831232);        // CB*4,718,592 B : ctx chunk

  int CB = 16;
  while (CB > 1 && 36831232ull + (size_t)CB * 4718592ull + 512ull > ws_size) CB >>= 1;
  int* sortedp = (int*)(ws + 36831232 + (size_t)CB * 4718592ull);  // 288 B

  k_ln<<<4096, 256, 0, stream>>>(hs, gamma, beta, xb);
  k_xt<<<dim3(16, 4, 16), 256, 0, stream>>>(xb, xt3);
  k_probs<<<9216, 256, 0, stream>>>(centers, spreads, probs_f, pb2);
  k_vwb<<<289, 256, 0, stream>>>(vw, vwb, centers, spreads, sortedp);
  for (int b0 = 0; b0 < 16; b0 += CB) {
    int c = (16 - b0) < CB ? (16 - b0) : CB;
    k_ctx<<<dim3(72 * c), 256, 0, stream>>>(pb2, xt3, centers, spreads, sortedp, ctx, b0, c);
    k_out<<<dim3(c*16), 512, 0, stream>>>(ctx, vwb, xb, vb, out, b0);
  }
}

// Round 7
// 109.275 us; speedup vs baseline: 1.2203x; 1.2203x over previous
//
#include <hip/hip_runtime.h>
#include <hip/hip_bf16.h>
#include <stdint.h>

typedef __bf16 bf16;
typedef __bf16 bf16x4 __attribute__((ext_vector_type(4)));
typedef __bf16 bf16x8 __attribute__((ext_vector_type(8)));
typedef float  f32x4  __attribute__((ext_vector_type(4)));

#define GLDS16(g, l) __builtin_amdgcn_global_load_lds(                      \
    (const __attribute__((address_space(1))) void*)(g),                     \
    (__attribute__((address_space(3))) void*)(l), 16, 0, 0)

#define BARX() do { __builtin_amdgcn_s_barrier();                            \
                    __builtin_amdgcn_sched_barrier(0); } while (0)
#define VMW(n) do { asm volatile("s_waitcnt vmcnt(" #n ")" ::: "memory");    \
                    __builtin_amdgcn_sched_barrier(0); } while (0)

// Truncation threshold: score cutoff s (drop cells with w < exp(-s/2) * max).
// s=18: truncated mass ~1e-3 relative, ~0.002 abs output error vs 0.03 bf16
// noise floor. (Was 28; NT avg 18 -> ~15.5, directly scales k_ctx work.)
#define TRUNC_S 18.0f

// ---------------- LayerNorm: (16,1024,256) f32 -> bf16 ----------------
__global__ __launch_bounds__(256) void k_ln(const float* __restrict__ hs,
                                            const float* __restrict__ gamma,
                                            const float* __restrict__ beta,
                                            bf16* __restrict__ xb) {
  int wid = threadIdx.x >> 6, lane = threadIdx.x & 63;
  size_t row = (size_t)blockIdx.x * 4 + wid;          // 16384 rows
  const float4* p = (const float4*)(hs + row * 256);
  float4 v = p[lane];
  float s  = v.x + v.y + v.z + v.w;
  float s2 = v.x*v.x + v.y*v.y + v.z*v.z + v.w*v.w;
#pragma unroll
  for (int o = 32; o; o >>= 1) { s += __shfl_xor(s, o); s2 += __shfl_xor(s2, o); }
  float mu  = s * (1.0f/256.0f);
  float var = s2 * (1.0f/256.0f) - mu*mu;
  float rs  = rsqrtf(var + 1e-5f);
  float4 g = ((const float4*)gamma)[lane];
  float4 b = ((const float4*)beta)[lane];
  bf16x4 o4;
  o4[0] = (bf16)((v.x - mu) * rs * g.x + b.x);
  o4[1] = (bf16)((v.y - mu) * rs * g.y + b.y);
  o4[2] = (bf16)((v.z - mu) * rs * g.z + b.z);
  o4[3] = (bf16)((v.w - mu) * rs * g.w + b.w);
  *(bf16x4*)(xb + row * 256 + lane * 4) = o4;
}

// ---------------- transpose xb[b][kl][d] -> xt[(b*256+d)][kl] ----------------
__global__ __launch_bounds__(256) void k_xt(const bf16* __restrict__ xb,
                                            bf16* __restrict__ xt) {
  __shared__ bf16 tile[64][65];
  int kl0 = blockIdx.x * 64, d0 = blockIdx.y * 64, b = blockIdx.z;
  int t = threadIdx.x;
  int r = t >> 2, c0 = (t & 3) * 16;
  const bf16* src = xb + ((size_t)(b * 1024 + kl0 + r)) * 256 + d0 + c0;
  bf16x8 v0 = *(const bf16x8*)src;
  bf16x8 v1 = *(const bf16x8*)(src + 8);
#pragma unroll
  for (int i = 0; i < 8; i++) { tile[r][c0 + i] = v0[i]; tile[r][c0 + 8 + i] = v1[i]; }
  __syncthreads();
  int dr = t >> 2, k0 = (t & 3) * 16;
  bf16x8 w0, w1;
#pragma unroll
  for (int i = 0; i < 8; i++) { w0[i] = tile[k0 + i][dr]; w1[i] = tile[k0 + 8 + i][dr]; }
  bf16* dst = xt + ((size_t)(b * 256 + d0 + dr)) * 1024 + kl0 + k0;
  *(bf16x8*)dst = w0;
  *(bf16x8*)(dst + 8) = w1;
}

// ------- vw f32 [256][2304] -> bf16, + fused LPT class sort (block 288) -------
__global__ __launch_bounds__(256) void k_vwb(const float* __restrict__ vw,
                                             bf16* __restrict__ vwb,
                                             const float* __restrict__ centers,
                                             const float* __restrict__ spreads,
                                             int* __restrict__ sorted) {
  __shared__ int nt[72];
  int t = threadIdx.x;
  if (blockIdx.x == 288) {         // LPT: rank 72 (h,mb) classes by NT desc
    if (t < 72) {
      int h = t >> 3, mb = t & 7;
      float S00 = spreads[h*4+0], S01 = spreads[h*4+1];
      float S10 = spreads[h*4+2], S11 = spreads[h*4+3];
      float a_ = S00*S00 + S01*S01;
      float b_ = S00*S10 + S01*S11;
      float c_ = S10*S10 + S11*S11;
      float mu1 = centers[h*2+0], mu2 = centers[h*2+1];
      float det = fmaxf(a_*c_ - b_*b_, 1e-6f);
      float A_ = a_*mu1 + b_*mu2;
      float B_ = c_ + mu2 + b_*mu1;
      float ustar = (c_*A_ - b_*B_) / det;
      float lam = fmaxf(a_ - b_*b_/c_, 1e-3f);
      float M_ = __fsqrt_rn(TRUNC_S / lam) + 1.5f;
      float lo_f = (float)(mb*4) + ustar, hi_f = lo_f + 3.0f;
      int k_lo = (int)floorf(fminf(lo_f, 31.0f) - M_);
      int k_hi = (int)ceilf(fmaxf(hi_f, 0.0f) + M_) + 1;
      if (k_lo < 0) k_lo = 0;
      if (k_hi > 32) k_hi = 32;
      if (k_hi <= k_lo) { k_lo = 0; k_hi = 32; }
      nt[t] = k_hi - k_lo;
    }
    __syncthreads();
    if (t < 72) {
      int my = nt[t], r = 0;
#pragma unroll 1
      for (int j = 0; j < 72; j++) {
        int v = nt[j];
        if (v > my || (v == my && j < t)) r++;
      }
      sorted[r] = t;          // class id = h*8 + mb
    }
    return;
  }
  int i = (blockIdx.x * 256 + t) * 8;
  float4 q0 = *(const float4*)(vw + i);
  float4 q1 = *(const float4*)(vw + i + 4);
  bf16x8 o;
  o[0]=(bf16)q0.x; o[1]=(bf16)q0.y; o[2]=(bf16)q0.z; o[3]=(bf16)q0.w;
  o[4]=(bf16)q1.x; o[5]=(bf16)q1.y; o[6]=(bf16)q1.z; o[7]=(bf16)q1.w;
  *(bf16x8*)(vwb + i) = o;
}

// -------- scores + softmax -> probs f32 (d_out) + pb2 bf16 [h][kt][ij][32] --------
__global__ __launch_bounds__(256) void k_probs(const float* __restrict__ centers,
                                               const float* __restrict__ spreads,
                                               float* __restrict__ pf,
                                               bf16* __restrict__ pb2) {
  int bid = blockIdx.x;          // ij*9 + h, 9216 blocks
  int h  = bid % 9;
  int ij = bid / 9;
  int i = ij >> 5, j = ij & 31;
  float S00 = spreads[h*4+0], S01 = spreads[h*4+1];
  float S10 = spreads[h*4+2], S11 = spreads[h*4+3];
  float a  = S00*S00 + S01*S01;
  float bq = S00*S10 + S01*S11;
  float c  = S10*S10 + S11*S11;
  float mu1 = centers[h*2+0], mu2 = centers[h*2+1];
  float u0 = a*mu1 + bq*mu2;
  float u1 = c + mu2 + bq*mu1;
  float u2 = -0.5f*a, u3 = -0.5f*c, u4 = -bq;
  int t = threadIdx.x;
  float sc[4]; float mx = -1e30f;
#pragma unroll
  for (int s = 0; s < 4; s++) {
    int kl = t*4 + s;
    float d0 = (float)((kl >> 5) - i);
    float d1 = (float)((kl & 31) - j);
    float v = d0*(u0 + u2*d0) + d1*(u1 + u3*d1) + u4*d0*d1;
    sc[s] = v; mx = fmaxf(mx, v);
  }
  __shared__ float red[8];
#pragma unroll
  for (int o = 32; o; o >>= 1) mx = fmaxf(mx, __shfl_xor(mx, o));
  int lane = t & 63, wid = t >> 6;
  if (lane == 0) red[wid] = mx;
  __syncthreads();
  mx = fmaxf(fmaxf(red[0], red[1]), fmaxf(red[2], red[3]));
  float sum = 0.f;
#pragma unroll
  for (int s = 0; s < 4; s++) { sc[s] = __expf(sc[s] - mx); sum += sc[s]; }
#pragma unroll
  for (int o = 32; o; o >>= 1) sum += __shfl_xor(sum, o);
  if (lane == 0) red[4 + wid] = sum;
  __syncthreads();
  sum = red[4] + red[5] + red[6] + red[7];
  float inv = 1.0f / sum;
  float4 o;
  o.x = sc[0]*inv; o.y = sc[1]*inv; o.z = sc[2]*inv; o.w = sc[3]*inv;
  *(float4*)(pf + (size_t)bid*1024 + t*4) = o;
  bf16x4 ob;
  ob[0] = (bf16)o.x; ob[1] = (bf16)o.y; ob[2] = (bf16)o.z; ob[3] = (bf16)o.w;
  // pb2[h][kt][ij][k%32]; thread t covers kl = t*4..t*4+3 (single 32-chunk)
  *(bf16x4*)(pb2 + ((size_t)(h*32 + (t >> 3))*1024 + ij)*32 + (t & 7)*4) = ob;
}

// swizzled fragment read: tiles are [R][32] bf16 linear, chunk' = chunk ^ ((row>>1)&3)
__device__ __forceinline__ bf16x8 frag_ld(const bf16* base, int row, int g) {
  return *(const bf16x8*)(base + row*32 + ((g ^ ((row >> 1) & 3)) << 3));
}

// ===== GEMM-A: ctx = P_h @ xt^T, 128(ij) x 256(d) tile, BK=32, K-trunc =====
// R5 structure (best measured): A direct-global from K-tile-major pb2,
// B in 3-buf LDS (48 KB), counted VMW(8), A ping-pong 2-unrolled.
__global__ __launch_bounds__(256, 2) void k_ctx(const bf16* __restrict__ pb2,
                                                const bf16* __restrict__ xt,
                                                const float* __restrict__ centers,
                                                const float* __restrict__ spreads,
                                                const int* __restrict__ sorted,
                                                bf16* __restrict__ ctx,
                                                int b0, int nbt) {
  __shared__ bf16 Bs[3*8192];     // [256][32] per buf (16 KB)
  int r_  = blockIdx.x / nbt;                       // class rank 0..71
  int nb  = blockIdx.x % nbt;                       // batch within chunk
  int cls = sorted[r_];
  int h   = cls >> 3;
  int mb  = cls & 7;
  int ij0 = mb * 128;                               // i in [mb*4, mb*4+4)
  int nrow0 = (b0 + nb) * 256;                      // xt rows for this batch

  int t = threadIdx.x, lane = t & 63, w = t >> 6;
  int wr = w >> 1, wc = w & 1;                      // wave: rows wr*64, cols wc*128
  int g = lane >> 4, rl = lane & 15;

  // ---- Gaussian k-support bounds (uniform per block; i-span 4) ----
  float S00 = spreads[h*4+0], S01 = spreads[h*4+1];
  float S10 = spreads[h*4+2], S11 = spreads[h*4+3];
  float a_ = S00*S00 + S01*S01;
  float b_ = S00*S10 + S01*S11;
  float c_ = S10*S10 + S11*S11;
  float mu1 = centers[h*2+0], mu2 = centers[h*2+1];
  float det = fmaxf(a_*c_ - b_*b_, 1e-6f);
  float A_ = a_*mu1 + b_*mu2;
  float B_ = c_ + mu2 + b_*mu1;
  float ustar = (c_*A_ - b_*B_) / det;
  float lam = fmaxf(a_ - b_*b_/c_, 1e-3f);
  float M_ = __fsqrt_rn(TRUNC_S / lam) + 1.5f;
  float lo_f = (float)(mb*4) + ustar, hi_f = lo_f + 3.0f;
  int k_lo = (int)floorf(fminf(lo_f, 31.0f) - M_);
  int k_hi = (int)ceilf(fmaxf(hi_f, 0.0f) + M_) + 1;
  if (k_lo < 0) k_lo = 0;
  if (k_hi > 32) k_hi = 32;
  if (k_hi <= k_lo) { k_lo = 0; k_hi = 32; }        // paranoia fallback
  const int NT = k_hi - k_lo;                       // 1..32 K-tiles of 32 kl

  f32x4 acc[4][8];
#pragma unroll
  for (int x_ = 0; x_ < 4; x_++)
#pragma unroll
    for (int y_ = 0; y_ < 8; y_++) acc[x_][y_] = (f32x4){0.f,0.f,0.f,0.f};

  // B staging: rows arow = t>>2 (64 per q-step), pre-swizzled chunk
  int arow = t >> 2;
  int acs  = (t & 3) ^ ((t >> 3) & 3);
  const bf16* b1 = xt + (size_t)(nrow0 + arow) * 1024 + k_lo*32 + acs * 8;
  // A direct-load base: pb2[h][k_lo+kt][ij0 + wr*64 + fr*16 + rl][g*8]
  const bf16* aP = pb2 + ((size_t)(h*32 + k_lo)*1024 + ij0 + wr*64 + rl)*32 + g*8;

#define STG(sb, kt) do {                                                    \
    _Pragma("unroll")                                                       \
    for (int q = 0; q < 4; q++)                                             \
      GLDS16(b1 + (size_t)q*64*1024 + (kt)*32,                              \
             ((char*)Bs) + (sb)*16384 + q*4096 + t*16);                     \
  } while (0)

#define LOADA(AF, kt) do {                                                  \
    const bf16* a_p = aP + (size_t)(kt)*32768;                              \
    _Pragma("unroll")                                                       \
    for (int fr = 0; fr < 4; fr++)                                          \
      AF[fr] = *(const bf16x8*)(a_p + fr*512);                              \
  } while (0)

#define MFM(AF, BF) do {                                                    \
    _Pragma("unroll")                                                       \
    for (int fr = 0; fr < 4; fr++)                                          \
      _Pragma("unroll")                                                     \
      for (int fn = 0; fn < 8; fn++)                                        \
        acc[fr][fn] = __builtin_amdgcn_mfma_f32_16x16x32_bf16(              \
            AF[fr], BF[fn], acc[fr][fn], 0, 0, 0);                          \
  } while (0)

  bf16x8 afA[4], afB[4];
  STG(0, 0);
  if (NT > 1) STG(1, 1);
  __builtin_amdgcn_sched_barrier(0);     // pin: B-stages issue before A-loads
  LOADA(afA, 0);
  if (NT > 1) VMW(8); else VMW(4);       // drain B(0); leave B(1)+A(0) in flight
  BARX();

  int cur = 0, kt = 0;
  while (true) {
    // ---- even step: consume afA for tile kt ----
    {
      bf16x8 bf_[8];
#pragma unroll
      for (int fn = 0; fn < 8; fn++) bf_[fn] = frag_ld(Bs + cur*8192, wc*128 + fn*16 + rl, g);
      int sb = cur + 2; if (sb >= 3) sb -= 3;
      if (kt + 2 < NT) STG(sb, kt + 2);
      __builtin_amdgcn_sched_barrier(0);
      if (kt + 1 < NT) LOADA(afB, kt + 1);
      MFM(afA, bf_);
      if (kt + 1 >= NT) break;
      if (kt + 2 < NT) VMW(8); else VMW(4);   // drain B(kt+1)
      BARX();
      cur = cur + 1; if (cur >= 3) cur = 0;
      kt++;
    }
    // ---- odd step: consume afB for tile kt ----
    {
      bf16x8 bf_[8];
#pragma unroll
      for (int fn = 0; fn < 8; fn++) bf_[fn] = frag_ld(Bs + cur*8192, wc*128 + fn*16 + rl, g);
      int sb = cur + 2; if (sb >= 3) sb -= 3;
      if (kt + 2 < NT) STG(sb, kt + 2);
      __builtin_amdgcn_sched_barrier(0);
      if (kt + 1 < NT) LOADA(afA, kt + 1);
      MFM(afB, bf_);
      if (kt + 1 >= NT) break;
      if (kt + 2 < NT) VMW(8); else VMW(4);   // drain B(kt+1)
      BARX();
      cur = cur + 1; if (cur >= 3) cur = 0;
      kt++;
    }
  }
#undef STG
#undef LOADA
#undef MFM

#pragma unroll
  for (int fr = 0; fr < 4; fr++) {
    int row = ij0 + wr*64 + fr*16 + g*4;            // ij
#pragma unroll
    for (int fn = 0; fn < 8; fn++) {
      int d = wc*128 + fn*16 + rl;                  // 0..255 within batch nb
      size_t base = ((size_t)nb*1024 + row) * 2304 + h*256 + d;
      f32x4 a4 = acc[fr][fn];
#pragma unroll
      for (int r = 0; r < 4; r++)
        ctx[base + (size_t)r*2304] = (bf16)a4[r];
    }
  }
}

// ======== GEMM-B: out[(b,ij)][m] = ctx(K2304) @ vwb^T + bias + x ========
// (R11 version — best measured.) 64 rows x FULL N=256 per block,
// 512 thr / 8 waves (wave 32x64), BK=64, 3-buf LDS (120 KB), counted VMW(5).
__global__ __launch_bounds__(512, 1) void k_out(const bf16* __restrict__ ctx,
                                                const bf16* __restrict__ vwb,
                                                const bf16* __restrict__ xb,
                                                const float* __restrict__ vbias,
                                                float* __restrict__ out, int b0) {
  __shared__ bf16 lds[3 * 20480];   // buf: A 64x64 (8KB) + B 256x64 (32KB) = 40KB
  int t = threadIdx.x, lane = t & 63, w = t >> 6;
  int wr = w >> 2, wc = w & 3;                       // wave tile: rows wr*32, cols wc*64
  int g = lane >> 4, rl = lane & 15;
  int r0 = blockIdx.x * 64;                          // chunk-local ctx row
  char* ldsb = (char*)lds;

  f32x4 acc[2][4];
#pragma unroll
  for (int x_ = 0; x_ < 2; x_++)
#pragma unroll
    for (int y_ = 0; y_ < 4; y_++) acc[x_][y_] = (f32x4){0.f,0.f,0.f,0.f};

  // staging: rr = t>>3 (64 rows), 8 chunks of 16B per 128B row, pre-swizzled
  int rr  = t >> 3;
  int csw = (t & 7) ^ (rr & 7);
  const bf16* aS = ctx + (size_t)(r0 + rr) * 2304 + csw * 8;
  const bf16* bS = vwb + (size_t)rr * 2304 + csw * 8;   // +q*64 rows per instr

#define STGO(sb, kt) do {                                                     \
    GLDS16(aS + (kt)*64, ldsb + (sb)*40960 + t*16);                           \
    _Pragma("unroll")                                                         \
    for (int q = 0; q < 4; q++)                                               \
      GLDS16(bS + (size_t)q*64*2304 + (kt)*64,                                \
             ldsb + (sb)*40960 + 8192 + q*8192 + t*16);                       \
  } while (0)

  STGO(0, 0); STGO(1, 1);
  VMW(5);                       // tile0 landed; tile1 in flight
  BARX();

  int cur = 0;
  for (int kt = 0; kt < 36; ++kt) {
    int sb = cur + 2; if (sb >= 3) sb -= 3;
    const char* ab = ldsb + cur*40960;
    const char* bb = ab + 8192;
    bf16x8 af0[2], af1[2], bf0[4], bf1[4];
#pragma unroll
    for (int fr = 0; fr < 2; fr++) {
      int row_ = wr*32 + fr*16 + rl;
      af0[fr] = *(const bf16x8*)(ab + row_*128 + (((g  ) ^ (row_&7)) << 4));
      af1[fr] = *(const bf16x8*)(ab + row_*128 + (((g+4) ^ (row_&7)) << 4));
    }
#pragma unroll
    for (int fn = 0; fn < 4; fn++) {
      int row_ = wc*64 + fn*16 + rl;
      bf0[fn] = *(const bf16x8*)(bb + row_*128 + (((g  ) ^ (row_&7)) << 4));
      bf1[fn] = *(const bf16x8*)(bb + row_*128 + (((g+4) ^ (row_&7)) << 4));
    }
    if (kt + 2 < 36) STGO(sb, kt + 2);
    BARX();
    __builtin_amdgcn_s_setprio(1);
#pragma unroll
    for (int fr = 0; fr < 2; fr++)
#pragma unroll
      for (int fn = 0; fn < 4; fn++) {
        acc[fr][fn] = __builtin_amdgcn_mfma_f32_16x16x32_bf16(af0[fr], bf0[fn], acc[fr][fn], 0, 0, 0);
        acc[fr][fn] = __builtin_amdgcn_mfma_f32_16x16x32_bf16(af1[fr], bf1[fn], acc[fr][fn], 0, 0, 0);
      }
    __builtin_amdgcn_s_setprio(0);
    if (kt + 2 < 36)      VMW(5);   // tile kt+1 landed; kt+2 in flight
    else if (kt + 1 < 36) VMW(0);   // last prefetched tile: drain all
    BARX();
    cur = cur + 1; if (cur >= 3) cur = 0;
  }
#undef STGO

#pragma unroll
  for (int fr = 0; fr < 2; fr++) {
    int rowl = r0 + wr*32 + fr*16 + g*4;
    size_t rowg = (size_t)b0*1024 + rowl;
#pragma unroll
    for (int fn = 0; fn < 4; fn++) {
      int m = wc*64 + fn*16 + rl;
      float bv = vbias[m];
      size_t base = rowg*256 + m;
#pragma unroll
      for (int r = 0; r < 4; r++)
        out[base + (size_t)r*256] = acc[fr][fn][r] + bv + (float)xb[base + (size_t)r*256];
    }
  }
}

extern "C" void kernel_launch(void* const* d_in, const int* in_sizes, int n_in,
                              void* d_out, int out_size, void* d_ws, size_t ws_size,
                              hipStream_t stream) {
  const float* hs      = (const float*)d_in[0];
  const float* centers = (const float*)d_in[1];
  const float* spreads = (const float*)d_in[2];
  const float* vw      = (const float*)d_in[3];
  const float* vb      = (const float*)d_in[4];
  const float* gamma   = (const float*)d_in[5];
  const float* beta    = (const float*)d_in[6];
  float* out     = (float*)d_out;
  float* probs_f = out + 4194304;            // output 0 is 16*32*32*256 f32

  char* ws = (char*)d_ws;
  bf16* xb  = (bf16*)ws;                     //  8,388,608 B : LN(x) bf16 [16384][256]
  bf16* pb2 = (bf16*)(ws + 8388608);         // 18,874,368 B : probs bf16 [9][32][1024][32]
  bf16* xt  = (bf16*)(ws + 27262976);        //  8,388,608 B : x^T bf16 [4096][1024]
  bf16* vwb = (bf16*)(ws + 35651584);        //  1,179,648 B : vw bf16 [256][2304]
  bf16* ctx = (bf16*)(ws + 36831232);        // CB*4,718,592 B : ctx chunk

  int CB = 16;
  while (CB > 1 && 36831232ull + (size_t)CB * 4718592ull + 512ull > ws_size) CB >>= 1;
  int* sortedp = (int*)(ws + 36831232 + (size_t)CB * 4718592ull);  // 288 B

  k_ln<<<4096, 256, 0, stream>>>(hs, gamma, beta, xb);
  k_xt<<<dim3(16, 4, 16), 256, 0, stream>>>(xb, xt);
  k_probs<<<9216, 256, 0, stream>>>(centers, spreads, probs_f, pb2);
  k_vwb<<<289, 256, 0, stream>>>(vw, vwb, centers, spreads, sortedp);
  for (int b0 = 0; b0 < 16; b0 += CB) {
    int c = (16 - b0) < CB ? (16 - b0) : CB;
    k_ctx<<<dim3(72 * c), 256, 0, stream>>>(pb2, xt, centers, spreads, sortedp, ctx, b0, c);
    k_out<<<dim3(c*16), 512, 0, stream>>>(ctx, vwb, xb, vb, out, b0);
  }
}

// Round 8
// 103.259 us; speedup vs baseline: 1.2913x; 1.0583x over previous
//
#include <hip/hip_runtime.h>
#include <hip/hip_bf16.h>
#include <stdint.h>

typedef __bf16 bf16;
typedef __bf16 bf16x4 __attribute__((ext_vector_type(4)));
typedef __bf16 bf16x8 __attribute__((ext_vector_type(8)));
typedef float  f32x4  __attribute__((ext_vector_type(4)));

#define GLDS16(g, l) __builtin_amdgcn_global_load_lds(                      \
    (const __attribute__((address_space(1))) void*)(g),                     \
    (__attribute__((address_space(3))) void*)(l), 16, 0, 0)

#define BARX() do { __builtin_amdgcn_s_barrier();                            \
                    __builtin_amdgcn_sched_barrier(0); } while (0)
#define VMW(n) do { asm volatile("s_waitcnt vmcnt(" #n ")" ::: "memory");    \
                    __builtin_amdgcn_sched_barrier(0); } while (0)

// Truncation threshold: score cutoff s (drop cells with w < exp(-s/2) * max).
// s=14: dropped weight <= e^-7 ~ 9e-4 rel, tail ~5e-3 -> ~6x under the 0.03
// bf16 noise floor. (History: 28 -> 18 [R7, absmax unchanged] -> 14.)
#define TRUNC_S 14.0f

// ------- fused LayerNorm + transpose -------
// hs f32 [16][1024][256] -> xb bf16 [b*1024+kl][256]  (k_out residual)
//                        -> xt bf16 [(b*256+d)][1024] (GEMM-A B operand)
// Block = (kl0 = 32 rows, b). 256 thr / 4 waves; wave-per-row LN (R-proven
// reduction), padded-LDS transpose (same [.][66] family as old k_xt).
__global__ __launch_bounds__(256) void k_lnt(const float* __restrict__ hs,
                                             const float* __restrict__ gamma,
                                             const float* __restrict__ beta,
                                             bf16* __restrict__ xb,
                                             bf16* __restrict__ xt) {
  __shared__ bf16 tile[4][32][66];   // 4 d-subtiles of 32 kl x 64 d (+2 pad)
  int kl0 = blockIdx.x * 32, b = blockIdx.y;
  int t = threadIdx.x, lane = t & 63, w = t >> 6;
  float4 g  = ((const float4*)gamma)[lane];
  float4 be = ((const float4*)beta)[lane];
  int sq = lane >> 4, col = (lane & 15) * 4;        // d-subtile, col within
#pragma unroll
  for (int i = 0; i < 8; i++) {
    int r = w * 8 + i;                               // local row 0..31
    size_t row = (size_t)b * 1024 + kl0 + r;
    float4 v = ((const float4*)(hs + row * 256))[lane];
    float s  = v.x + v.y + v.z + v.w;
    float s2 = v.x*v.x + v.y*v.y + v.z*v.z + v.w*v.w;
#pragma unroll
    for (int o = 32; o; o >>= 1) { s += __shfl_xor(s, o); s2 += __shfl_xor(s2, o); }
    float mu = s * (1.0f/256.0f);
    float var = s2 * (1.0f/256.0f) - mu*mu;
    float rs = rsqrtf(var + 1e-5f);
    bf16x4 o4;
    o4[0] = (bf16)((v.x - mu) * rs * g.x + be.x);
    o4[1] = (bf16)((v.y - mu) * rs * g.y + be.y);
    o4[2] = (bf16)((v.z - mu) * rs * g.z + be.z);
    o4[3] = (bf16)((v.w - mu) * rs * g.w + be.w);
    *(bf16x4*)(xb + row * 256 + lane * 4) = o4;
    *(bf16x4*)(&tile[sq][r][col]) = o4;
  }
  __syncthreads();
  // transposed write: thread covers dr = t>>2 (0..63), k0 = (t&3)*8 (8 k's)
  int dr = t >> 2, k0 = (t & 3) * 8;
#pragma unroll
  for (int q = 0; q < 4; q++) {
    bf16x8 w0;
#pragma unroll
    for (int i = 0; i < 8; i++) w0[i] = tile[q][k0 + i][dr];
    *(bf16x8*)(xt + ((size_t)(b * 256 + q * 64 + dr)) * 1024 + kl0 + k0) = w0;
  }
}

// ------- vw f32 [256][2304] -> bf16, + fused LPT class sort (block 288) -------
__global__ __launch_bounds__(256) void k_vwb(const float* __restrict__ vw,
                                             bf16* __restrict__ vwb,
                                             const float* __restrict__ centers,
                                             const float* __restrict__ spreads,
                                             int* __restrict__ sorted) {
  __shared__ int nt[72];
  int t = threadIdx.x;
  if (blockIdx.x == 288) {         // LPT: rank 72 (h,mb) classes by NT desc
    if (t < 72) {
      int h = t >> 3, mb = t & 7;
      float S00 = spreads[h*4+0], S01 = spreads[h*4+1];
      float S10 = spreads[h*4+2], S11 = spreads[h*4+3];
      float a_ = S00*S00 + S01*S01;
      float b_ = S00*S10 + S01*S11;
      float c_ = S10*S10 + S11*S11;
      float mu1 = centers[h*2+0], mu2 = centers[h*2+1];
      float det = fmaxf(a_*c_ - b_*b_, 1e-6f);
      float A_ = a_*mu1 + b_*mu2;
      float B_ = c_ + mu2 + b_*mu1;
      float ustar = (c_*A_ - b_*B_) / det;
      float lam = fmaxf(a_ - b_*b_/c_, 1e-3f);
      float M_ = __fsqrt_rn(TRUNC_S / lam) + 1.5f;
      float lo_f = (float)(mb*4) + ustar, hi_f = lo_f + 3.0f;
      int k_lo = (int)floorf(fminf(lo_f, 31.0f) - M_);
      int k_hi = (int)ceilf(fmaxf(hi_f, 0.0f) + M_) + 1;
      if (k_lo < 0) k_lo = 0;
      if (k_hi > 32) k_hi = 32;
      if (k_hi <= k_lo) { k_lo = 0; k_hi = 32; }
      nt[t] = k_hi - k_lo;
    }
    __syncthreads();
    if (t < 72) {
      int my = nt[t], r = 0;
#pragma unroll 1
      for (int j = 0; j < 72; j++) {
        int v = nt[j];
        if (v > my || (v == my && j < t)) r++;
      }
      sorted[r] = t;          // class id = h*8 + mb
    }
    return;
  }
  int i = (blockIdx.x * 256 + t) * 8;
  float4 q0 = *(const float4*)(vw + i);
  float4 q1 = *(const float4*)(vw + i + 4);
  bf16x8 o;
  o[0]=(bf16)q0.x; o[1]=(bf16)q0.y; o[2]=(bf16)q0.z; o[3]=(bf16)q0.w;
  o[4]=(bf16)q1.x; o[5]=(bf16)q1.y; o[6]=(bf16)q1.z; o[7]=(bf16)q1.w;
  *(bf16x8*)(vwb + i) = o;
}

// -------- scores + softmax -> probs f32 (d_out) + pb2 bf16 [h][kt][ij][32] --------
__global__ __launch_bounds__(256) void k_probs(const float* __restrict__ centers,
                                               const float* __restrict__ spreads,
                                               float* __restrict__ pf,
                                               bf16* __restrict__ pb2) {
  int bid = blockIdx.x;          // ij*9 + h, 9216 blocks
  int h  = bid % 9;
  int ij = bid / 9;
  int i = ij >> 5, j = ij & 31;
  float S00 = spreads[h*4+0], S01 = spreads[h*4+1];
  float S10 = spreads[h*4+2], S11 = spreads[h*4+3];
  float a  = S00*S00 + S01*S01;
  float bq = S00*S10 + S01*S11;
  float c  = S10*S10 + S11*S11;
  float mu1 = centers[h*2+0], mu2 = centers[h*2+1];
  float u0 = a*mu1 + bq*mu2;
  float u1 = c + mu2 + bq*mu1;
  float u2 = -0.5f*a, u3 = -0.5f*c, u4 = -bq;
  int t = threadIdx.x;
  float sc[4]; float mx = -1e30f;
#pragma unroll
  for (int s = 0; s < 4; s++) {
    int kl = t*4 + s;
    float d0 = (float)((kl >> 5) - i);
    float d1 = (float)((kl & 31) - j);
    float v = d0*(u0 + u2*d0) + d1*(u1 + u3*d1) + u4*d0*d1;
    sc[s] = v; mx = fmaxf(mx, v);
  }
  __shared__ float red[8];
#pragma unroll
  for (int o = 32; o; o >>= 1) mx = fmaxf(mx, __shfl_xor(mx, o));
  int lane = t & 63, wid = t >> 6;
  if (lane == 0) red[wid] = mx;
  __syncthreads();
  mx = fmaxf(fmaxf(red[0], red[1]), fmaxf(red[2], red[3]));
  float sum = 0.f;
#pragma unroll
  for (int s = 0; s < 4; s++) { sc[s] = __expf(sc[s] - mx); sum += sc[s]; }
#pragma unroll
  for (int o = 32; o; o >>= 1) sum += __shfl_xor(sum, o);
  if (lane == 0) red[4 + wid] = sum;
  __syncthreads();
  sum = red[4] + red[5] + red[6] + red[7];
  float inv = 1.0f / sum;
  float4 o;
  o.x = sc[0]*inv; o.y = sc[1]*inv; o.z = sc[2]*inv; o.w = sc[3]*inv;
  *(float4*)(pf + (size_t)bid*1024 + t*4) = o;
  bf16x4 ob;
  ob[0] = (bf16)o.x; ob[1] = (bf16)o.y; ob[2] = (bf16)o.z; ob[3] = (bf16)o.w;
  // pb2[h][kt][ij][k%32]; thread t covers kl = t*4..t*4+3 (single 32-chunk)
  *(bf16x4*)(pb2 + ((size_t)(h*32 + (t >> 3))*1024 + ij)*32 + (t & 7)*4) = ob;
}

// swizzled fragment read: tiles are [R][32] bf16 linear, chunk' = chunk ^ ((row>>1)&3)
__device__ __forceinline__ bf16x8 frag_ld(const bf16* base, int row, int g) {
  return *(const bf16x8*)(base + row*32 + ((g ^ ((row >> 1) & 3)) << 3));
}

// ===== GEMM-A: ctx = P_h @ xt^T, 128(ij) x 256(d) tile, BK=32, K-trunc =====
// R5 structure (best measured): A direct-global from K-tile-major pb2,
// B in 3-buf LDS (48 KB), counted VMW(8), A ping-pong 2-unrolled.
__global__ __launch_bounds__(256, 2) void k_ctx(const bf16* __restrict__ pb2,
                                                const bf16* __restrict__ xt,
                                                const float* __restrict__ centers,
                                                const float* __restrict__ spreads,
                                                const int* __restrict__ sorted,
                                                bf16* __restrict__ ctx,
                                                int b0, int nbt) {
  __shared__ bf16 Bs[3*8192];     // [256][32] per buf (16 KB)
  int r_  = blockIdx.x / nbt;                       // class rank 0..71
  int nb  = blockIdx.x % nbt;                       // batch within chunk
  int cls = sorted[r_];
  int h   = cls >> 3;
  int mb  = cls & 7;
  int ij0 = mb * 128;                               // i in [mb*4, mb*4+4)
  int nrow0 = (b0 + nb) * 256;                      // xt rows for this batch

  int t = threadIdx.x, lane = t & 63, w = t >> 6;
  int wr = w >> 1, wc = w & 1;                      // wave: rows wr*64, cols wc*128
  int g = lane >> 4, rl = lane & 15;

  // ---- Gaussian k-support bounds (uniform per block; i-span 4) ----
  float S00 = spreads[h*4+0], S01 = spreads[h*4+1];
  float S10 = spreads[h*4+2], S11 = spreads[h*4+3];
  float a_ = S00*S00 + S01*S01;
  float b_ = S00*S10 + S01*S11;
  float c_ = S10*S10 + S11*S11;
  float mu1 = centers[h*2+0], mu2 = centers[h*2+1];
  float det = fmaxf(a_*c_ - b_*b_, 1e-6f);
  float A_ = a_*mu1 + b_*mu2;
  float B_ = c_ + mu2 + b_*mu1;
  float ustar = (c_*A_ - b_*B_) / det;
  float lam = fmaxf(a_ - b_*b_/c_, 1e-3f);
  float M_ = __fsqrt_rn(TRUNC_S / lam) + 1.5f;
  float lo_f = (float)(mb*4) + ustar, hi_f = lo_f + 3.0f;
  int k_lo = (int)floorf(fminf(lo_f, 31.0f) - M_);
  int k_hi = (int)ceilf(fmaxf(hi_f, 0.0f) + M_) + 1;
  if (k_lo < 0) k_lo = 0;
  if (k_hi > 32) k_hi = 32;
  if (k_hi <= k_lo) { k_lo = 0; k_hi = 32; }        // paranoia fallback
  const int NT = k_hi - k_lo;                       // 1..32 K-tiles of 32 kl

  f32x4 acc[4][8];
#pragma unroll
  for (int x_ = 0; x_ < 4; x_++)
#pragma unroll
    for (int y_ = 0; y_ < 8; y_++) acc[x_][y_] = (f32x4){0.f,0.f,0.f,0.f};

  // B staging: rows arow = t>>2 (64 per q-step), pre-swizzled chunk
  int arow = t >> 2;
  int acs  = (t & 3) ^ ((t >> 3) & 3);
  const bf16* b1 = xt + (size_t)(nrow0 + arow) * 1024 + k_lo*32 + acs * 8;
  // A direct-load base: pb2[h][k_lo+kt][ij0 + wr*64 + fr*16 + rl][g*8]
  const bf16* aP = pb2 + ((size_t)(h*32 + k_lo)*1024 + ij0 + wr*64 + rl)*32 + g*8;

#define STG(sb, kt) do {                                                    \
    _Pragma("unroll")                                                       \
    for (int q = 0; q < 4; q++)                                             \
      GLDS16(b1 + (size_t)q*64*1024 + (kt)*32,                              \
             ((char*)Bs) + (sb)*16384 + q*4096 + t*16);                     \
  } while (0)

#define LOADA(AF, kt) do {                                                  \
    const bf16* a_p = aP + (size_t)(kt)*32768;                              \
    _Pragma("unroll")                                                       \
    for (int fr = 0; fr < 4; fr++)                                          \
      AF[fr] = *(const bf16x8*)(a_p + fr*512);                              \
  } while (0)

#define MFM(AF, BF) do {                                                    \
    _Pragma("unroll")                                                       \
    for (int fr = 0; fr < 4; fr++)                                          \
      _Pragma("unroll")                                                     \
      for (int fn = 0; fn < 8; fn++)                                        \
        acc[fr][fn] = __builtin_amdgcn_mfma_f32_16x16x32_bf16(              \
            AF[fr], BF[fn], acc[fr][fn], 0, 0, 0);                          \
  } while (0)

  bf16x8 afA[4], afB[4];
  STG(0, 0);
  if (NT > 1) STG(1, 1);
  __builtin_amdgcn_sched_barrier(0);     // pin: B-stages issue before A-loads
  LOADA(afA, 0);
  if (NT > 1) VMW(8); else VMW(4);       // drain B(0); leave B(1)+A(0) in flight
  BARX();

  int cur = 0, kt = 0;
  while (true) {
    // ---- even step: consume afA for tile kt ----
    {
      bf16x8 bf_[8];
#pragma unroll
      for (int fn = 0; fn < 8; fn++) bf_[fn] = frag_ld(Bs + cur*8192, wc*128 + fn*16 + rl, g);
      int sb = cur + 2; if (sb >= 3) sb -= 3;
      if (kt + 2 < NT) STG(sb, kt + 2);
      __builtin_amdgcn_sched_barrier(0);
      if (kt + 1 < NT) LOADA(afB, kt + 1);
      MFM(afA, bf_);
      if (kt + 1 >= NT) break;
      if (kt + 2 < NT) VMW(8); else VMW(4);   // drain B(kt+1)
      BARX();
      cur = cur + 1; if (cur >= 3) cur = 0;
      kt++;
    }
    // ---- odd step: consume afB for tile kt ----
    {
      bf16x8 bf_[8];
#pragma unroll
      for (int fn = 0; fn < 8; fn++) bf_[fn] = frag_ld(Bs + cur*8192, wc*128 + fn*16 + rl, g);
      int sb = cur + 2; if (sb >= 3) sb -= 3;
      if (kt + 2 < NT) STG(sb, kt + 2);
      __builtin_amdgcn_sched_barrier(0);
      if (kt + 1 < NT) LOADA(afA, kt + 1);
      MFM(afB, bf_);
      if (kt + 1 >= NT) break;
      if (kt + 2 < NT) VMW(8); else VMW(4);   // drain B(kt+1)
      BARX();
      cur = cur + 1; if (cur >= 3) cur = 0;
      kt++;
    }
  }
#undef STG
#undef LOADA
#undef MFM

#pragma unroll
  for (int fr = 0; fr < 4; fr++) {
    int row = ij0 + wr*64 + fr*16 + g*4;            // ij
#pragma unroll
    for (int fn = 0; fn < 8; fn++) {
      int d = wc*128 + fn*16 + rl;                  // 0..255 within batch nb
      size_t base = ((size_t)nb*1024 + row) * 2304 + h*256 + d;
      f32x4 a4 = acc[fr][fn];
#pragma unroll
      for (int r = 0; r < 4; r++)
        ctx[base + (size_t)r*2304] = (bf16)a4[r];
    }
  }
}

// ======== GEMM-B: out[(b,ij)][m] = ctx(K2304) @ vwb^T + bias + x ========
// (R11 version — best measured.) 64 rows x FULL N=256 per block,
// 512 thr / 8 waves (wave 32x64), BK=64, 3-buf LDS (120 KB), counted VMW(5).
__global__ __launch_bounds__(512, 1) void k_out(const bf16* __restrict__ ctx,
                                                const bf16* __restrict__ vwb,
                                                const bf16* __restrict__ xb,
                                                const float* __restrict__ vbias,
                                                float* __restrict__ out, int b0) {
  __shared__ bf16 lds[3 * 20480];   // buf: A 64x64 (8KB) + B 256x64 (32KB) = 40KB
  int t = threadIdx.x, lane = t & 63, w = t >> 6;
  int wr = w >> 2, wc = w & 3;                       // wave tile: rows wr*32, cols wc*64
  int g = lane >> 4, rl = lane & 15;
  int r0 = blockIdx.x * 64;                          // chunk-local ctx row
  char* ldsb = (char*)lds;

  f32x4 acc[2][4];
#pragma unroll
  for (int x_ = 0; x_ < 2; x_++)
#pragma unroll
    for (int y_ = 0; y_ < 4; y_++) acc[x_][y_] = (f32x4){0.f,0.f,0.f,0.f};

  // staging: rr = t>>3 (64 rows), 8 chunks of 16B per 128B row, pre-swizzled
  int rr  = t >> 3;
  int csw = (t & 7) ^ (rr & 7);
  const bf16* aS = ctx + (size_t)(r0 + rr) * 2304 + csw * 8;
  const bf16* bS = vwb + (size_t)rr * 2304 + csw * 8;   // +q*64 rows per instr

#define STGO(sb, kt) do {                                                     \
    GLDS16(aS + (kt)*64, ldsb + (sb)*40960 + t*16);                           \
    _Pragma("unroll")                                                         \
    for (int q = 0; q < 4; q++)                                               \
      GLDS16(bS + (size_t)q*64*2304 + (kt)*64,                                \
             ldsb + (sb)*40960 + 8192 + q*8192 + t*16);                       \
  } while (0)

  STGO(0, 0); STGO(1, 1);
  VMW(5);                       // tile0 landed; tile1 in flight
  BARX();

  int cur = 0;
  for (int kt = 0; kt < 36; ++kt) {
    int sb = cur + 2; if (sb >= 3) sb -= 3;
    const char* ab = ldsb + cur*40960;
    const char* bb = ab + 8192;
    bf16x8 af0[2], af1[2], bf0[4], bf1[4];
#pragma unroll
    for (int fr = 0; fr < 2; fr++) {
      int row_ = wr*32 + fr*16 + rl;
      af0[fr] = *(const bf16x8*)(ab + row_*128 + (((g  ) ^ (row_&7)) << 4));
      af1[fr] = *(const bf16x8*)(ab + row_*128 + (((g+4) ^ (row_&7)) << 4));
    }
#pragma unroll
    for (int fn = 0; fn < 4; fn++) {
      int row_ = wc*64 + fn*16 + rl;
      bf0[fn] = *(const bf16x8*)(bb + row_*128 + (((g  ) ^ (row_&7)) << 4));
      bf1[fn] = *(const bf16x8*)(bb + row_*128 + (((g+4) ^ (row_&7)) << 4));
    }
    if (kt + 2 < 36) STGO(sb, kt + 2);
    BARX();
    __builtin_amdgcn_s_setprio(1);
#pragma unroll
    for (int fr = 0; fr < 2; fr++)
#pragma unroll
      for (int fn = 0; fn < 4; fn++) {
        acc[fr][fn] = __builtin_amdgcn_mfma_f32_16x16x32_bf16(af0[fr], bf0[fn], acc[fr][fn], 0, 0, 0);
        acc[fr][fn] = __builtin_amdgcn_mfma_f32_16x16x32_bf16(af1[fr], bf1[fn], acc[fr][fn], 0, 0, 0);
      }
    __builtin_amdgcn_s_setprio(0);
    if (kt + 2 < 36)      VMW(5);   // tile kt+1 landed; kt+2 in flight
    else if (kt + 1 < 36) VMW(0);   // last prefetched tile: drain all
    BARX();
    cur = cur + 1; if (cur >= 3) cur = 0;
  }
#undef STGO

#pragma unroll
  for (int fr = 0; fr < 2; fr++) {
    int rowl = r0 + wr*32 + fr*16 + g*4;
    size_t rowg = (size_t)b0*1024 + rowl;
#pragma unroll
    for (int fn = 0; fn < 4; fn++) {
      int m = wc*64 + fn*16 + rl;
      float bv = vbias[m];
      size_t base = rowg*256 + m;
#pragma unroll
      for (int r = 0; r < 4; r++)
        out[base + (size_t)r*256] = acc[fr][fn][r] + bv + (float)xb[base + (size_t)r*256];
    }
  }
}

extern "C" void kernel_launch(void* const* d_in, const int* in_sizes, int n_in,
                              void* d_out, int out_size, void* d_ws, size_t ws_size,
                              hipStream_t stream) {
  const float* hs      = (const float*)d_in[0];
  const float* centers = (const float*)d_in[1];
  const float* spreads = (const float*)d_in[2];
  const float* vw      = (const float*)d_in[3];
  const float* vb      = (const float*)d_in[4];
  const float* gamma   = (const float*)d_in[5];
  const float* beta    = (const float*)d_in[6];
  float* out     = (float*)d_out;
  float* probs_f = out + 4194304;            // output 0 is 16*32*32*256 f32

  char* ws = (char*)d_ws;
  bf16* xb  = (bf16*)ws;                     //  8,388,608 B : LN(x) bf16 [16384][256]
  bf16* pb2 = (bf16*)(ws + 8388608);         // 18,874,368 B : probs bf16 [9][32][1024][32]
  bf16* xt  = (bf16*)(ws + 27262976);        //  8,388,608 B : x^T bf16 [4096][1024]
  bf16* vwb = (bf16*)(ws + 35651584);        //  1,179,648 B : vw bf16 [256][2304]
  bf16* ctx = (bf16*)(ws + 36831232);        // CB*4,718,592 B : ctx chunk

  int CB = 16;
  while (CB > 1 && 36831232ull + (size_t)CB * 4718592ull + 512ull > ws_size) CB >>= 1;
  int* sortedp = (int*)(ws + 36831232 + (size_t)CB * 4718592ull);  // 288 B

  k_lnt<<<dim3(32, 16), 256, 0, stream>>>(hs, gamma, beta, xb, xt);
  k_probs<<<9216, 256, 0, stream>>>(centers, spreads, probs_f, pb2);
  k_vwb<<<289, 256, 0, stream>>>(vw, vwb, centers, spreads, sortedp);
  for (int b0 = 0; b0 < 16; b0 += CB) {
    int c = (16 - b0) < CB ? (16 - b0) : CB;
    k_ctx<<<dim3(72 * c), 256, 0, stream>>>(pb2, xt, centers, spreads, sortedp, ctx, b0, c);
    k_out<<<dim3(c*16), 512, 0, stream>>>(ctx, vwb, xb, vb, out, b0);
  }
}